// Round 7
// baseline (1156.593 us; speedup 1.0000x reference)
//
#include <hip/hip_runtime.h>
#include <hip/hip_bf16.h>

#define VOCAB 32000
#define EMBED 512
#define HIDDEN 1024
#define NB 8
#define NT 256
#define XH_ROWS 16

#define NCH 8      // independent chains (= batch)
#define NMEM 32    // blocks per chain
#define RCOLS 32   // hidden columns per block

typedef __attribute__((ext_vector_type(8))) short bf16x8;
typedef __attribute__((ext_vector_type(4))) float f32x4;

__device__ __forceinline__ unsigned short bf16_bits(float f) {
    __hip_bfloat16 b = __float2bfloat16(f);
    unsigned short s;
    __builtin_memcpy(&s, &b, 2);
    return s;
}

// ---------------- W_hy [HIDDEN][VOCAB] f32 -> Wt [VOCAB][HIDDEN] bf16 ----------------
__global__ __launch_bounds__(256) void k_transpose(const float* __restrict__ W,
                                                   __hip_bfloat16* __restrict__ Wt) {
    __shared__ float tile[32][33];
    const int n0 = blockIdx.x * 32;
    const int k0 = blockIdx.y * 32;
    const int c = threadIdx.x & 31;
    const int r0 = threadIdx.x >> 5;
#pragma unroll
    for (int rr = 0; rr < 4; ++rr) {
        const int r = r0 + rr * 8;
        tile[c][r] = W[(size_t)(k0 + r) * VOCAB + n0 + c];
    }
    __syncthreads();
#pragma unroll
    for (int rr = 0; rr < 4; ++rr) {
        const int n = r0 + rr * 8;
        Wt[(size_t)(n0 + n) * HIDDEN + k0 + c] = __float2bfloat16(tile[n][c]);
    }
}

// ---------------- xh = emb[x] @ W_xh + b_h  (fp32) ----------------
__global__ __launch_bounds__(256) void k_xh(const int* __restrict__ ids,
                                            const float* __restrict__ emb,
                                            const float* __restrict__ Wxh,
                                            const float* __restrict__ bh,
                                            float* __restrict__ xh) {
    __shared__ alignas(16) float embS[XH_ROWS][EMBED];
    __shared__ int idsS[XH_ROWS];
    const int tid = threadIdx.x;
    const int blk = blockIdx.x;
    if (tid < XH_ROWS) idsS[tid] = ids[blk * XH_ROWS + tid];
    __syncthreads();
    const float4* emb4 = (const float4*)emb;
#pragma unroll
    for (int rep = 0; rep < (XH_ROWS * EMBED / 4) / 256; ++rep) {
        const int lin = rep * 256 + tid;
        const int r = lin >> 7;
        const int e4 = lin & 127;
        *(float4*)&embS[r][e4 * 4] = emb4[(size_t)idsS[r] * (EMBED / 4) + e4];
    }
    __syncthreads();
    float4 acc[XH_ROWS] = {};
    const float4* W4 = (const float4*)Wxh;
    for (int e = 0; e < EMBED; ++e) {
        const float4 w = W4[(size_t)e * (HIDDEN / 4) + tid];
#pragma unroll
        for (int r = 0; r < XH_ROWS; ++r) {
            const float ev = embS[r][e];
            acc[r].x += ev * w.x; acc[r].y += ev * w.y;
            acc[r].z += ev * w.z; acc[r].w += ev * w.w;
        }
    }
    const float4 bv = ((const float4*)bh)[tid];
#pragma unroll
    for (int r = 0; r < XH_ROWS; ++r) {
        float4 o;
        o.x = acc[r].x + bv.x; o.y = acc[r].y + bv.y;
        o.z = acc[r].z + bv.z; o.w = acc[r].w + bv.w;
        ((float4*)xh)[(size_t)(blk * XH_ROWS + r) * (HIDDEN / 4) + tid] = o;
    }
}

// ---------------- persistent recurrence: u64 token-in-data, 8 chains x 32 members ----------------
// One u64 = token(low16) | bf16 h[2w]<<16 | bf16 h[2w+1]<<32. Producers fire-and-forget
// relaxed agent stores; consumers poll 2 independent u64 per thread in one combined
// retry loop. Double buffer + exact-token match is deadlock-free (induction over steps)
// and replay-safe (stale tokens 255/256 never match expected 0/1).
// Bank-conflict fixes this round: per-part rotated h read (banks 4-distinct/wave,
// accumulation order-independent) and red stride 33.
__global__ __launch_bounds__(256, 1) void k_rec(const float* __restrict__ Whh,
                                                const float* __restrict__ xh,
                                                unsigned long long* __restrict__ hx,
                                                __hip_bfloat16* __restrict__ hs) {
    __shared__ unsigned WstU[16 * 1032];   // [part][ii*16+col2], part-padded: 66 KB
    __shared__ float xhS[NT * RCOLS];      // 32 KB, [t][col]
    __shared__ float hS[1024];             // 4 KB
    __shared__ float red[16 * 33];         // 2.1 KB, stride-33 (write banks 2-way)
    const int tid = threadIdx.x;
    const int bid = blockIdx.x;
    const int c = bid & (NCH - 1);     // chain (bid%8 ~ XCD round robin)
    const int m = bid >> 3;            // member 0..31
    const int j0 = m * RCOLS;
    unsigned long long* hxc = hx + (size_t)c * 1024;   // [2][512] u64 words

    // h_{-1} = 0 with token 0 lives in buf[1]; this member's 16 words
    if (tid < 16)
        __hip_atomic_store(&hxc[512 + m * 16 + tid], 0ull, __ATOMIC_RELAXED,
                           __HIP_MEMORY_SCOPE_AGENT);

    // pack W_hh slice: row i = part*64+ii, cols j0+2*col2, j0+2*col2+1
    for (int lin = tid; lin < 16 * 64 * 16; lin += 256) {
        const int part = lin >> 10;
        const int rem = lin & 1023;
        const int ii = rem >> 4;
        const int col2 = rem & 15;
        const int i = part * 64 + ii;
        const float2 w = *(const float2*)&Whh[(size_t)i * HIDDEN + j0 + 2 * col2];
        WstU[part * 1032 + ii * 16 + col2] =
            (unsigned)bf16_bits(w.x) | ((unsigned)bf16_bits(w.y) << 16);
    }
    // pre-stage this block's xh slice: [256][32]
    for (int idx = tid; idx < NT * RCOLS; idx += 256) {
        const int t = idx >> 5;
        const int col = idx & 31;
        xhS[idx] = xh[(size_t)(c * NT + t) * HIDDEN + j0 + col];
    }
    __syncthreads();

    const int col2 = tid & 15;
    const int part = tid >> 4;
    const int rot = (4 * part) & 63;       // per-part read rotation (bank spread)
    const unsigned* Wp = &WstU[part * 1032 + col2];
    const float* hp = &hS[part * 64];
    const int w0 = tid;          // u64 word indices this thread polls
    const int w1 = tid + 256;

    for (int t = 0; t < NT; ++t) {
        unsigned long long* rbuf = hxc + ((t + 1) & 1) * 512;  // h_{t-1}, tokens == t
        unsigned long long* wbuf = hxc + (t & 1) * 512;        // we write h_t, token t+1
        const unsigned long long tok = (unsigned long long)(unsigned)t;
        // combined poll: both loads independent & in flight before the check
        unsigned long long a = __hip_atomic_load(&rbuf[w0], __ATOMIC_RELAXED, __HIP_MEMORY_SCOPE_AGENT);
        unsigned long long b = __hip_atomic_load(&rbuf[w1], __ATOMIC_RELAXED, __HIP_MEMORY_SCOPE_AGENT);
        while (((a & 0xffffull) != tok) | ((b & 0xffffull) != tok)) {
            __builtin_amdgcn_s_sleep(1);
            if ((a & 0xffffull) != tok)
                a = __hip_atomic_load(&rbuf[w0], __ATOMIC_RELAXED, __HIP_MEMORY_SCOPE_AGENT);
            if ((b & 0xffffull) != tok)
                b = __hip_atomic_load(&rbuf[w1], __ATOMIC_RELAXED, __HIP_MEMORY_SCOPE_AGENT);
        }
        *(float2*)&hS[2 * w0] = make_float2(__uint_as_float(((unsigned)(a >> 16) & 0xffffu) << 16),
                                            __uint_as_float(((unsigned)(a >> 32) & 0xffffu) << 16));
        *(float2*)&hS[2 * w1] = make_float2(__uint_as_float(((unsigned)(b >> 16) & 0xffffu) << 16),
                                            __uint_as_float(((unsigned)(b >> 32) & 0xffffu) << 16));
        __syncthreads();
        float a0 = 0.f, a1 = 0.f;
#pragma unroll 8
        for (int ii = 0; ii < 64; ++ii) {
            const int idx = (ii + rot) & 63;
            const unsigned u = Wp[idx * 16];
            const float hv = hp[idx];
            a0 = fmaf(__uint_as_float(u << 16), hv, a0);
            a1 = fmaf(__uint_as_float(u & 0xffff0000u), hv, a1);
        }
        red[part * 33 + 2 * col2]     = a0;
        red[part * 33 + 2 * col2 + 1] = a1;
        __syncthreads();
        if (tid < RCOLS) {
            float s = 0.f;
#pragma unroll
            for (int p = 0; p < 16; ++p) s += red[p * 33 + tid];
            const float v = tanhf(xhS[t * RCOLS + tid] + s);
            const unsigned hb = (unsigned)bf16_bits(v);
            ((unsigned short*)hs)[(size_t)(c * NT + t) * HIDDEN + j0 + tid] = (unsigned short)hb;
            const unsigned pb = (unsigned)__shfl_xor((int)hb, 1, 64);
            if ((tid & 1) == 0) {
                const unsigned long long wv = (unsigned long long)(unsigned)(t + 1)
                                            | ((unsigned long long)hb << 16)
                                            | ((unsigned long long)pb << 32);
                __hip_atomic_store(&wbuf[m * 16 + (tid >> 1)], wv, __ATOMIC_RELAXED,
                                   __HIP_MEMORY_SCOPE_AGENT);
            }
        }
        // no block barrier: next step's hS writes are gated by the token poll,
        // which can't pass until this block produced its own words.
    }
}

// ---------------- y = hs @ Wt^T + b_y  (bf16 MFMA, m97-style: global_load_lds) ----------------
__global__ __launch_bounds__(256) void k_proj(const __hip_bfloat16* __restrict__ A,   // [2048][1024]
                                              const __hip_bfloat16* __restrict__ Bt,  // [32000][1024]
                                              const float* __restrict__ by,
                                              float* __restrict__ C) {
    __shared__ __hip_bfloat16 At[128 * 32];    // linear: required by global_load_lds
    __shared__ __hip_bfloat16 Bts[128 * 32];
    const int tid = threadIdx.x;
    // bijective XCD-chunked swizzle (4000 % 8 == 0): consecutive swz ids (which
    // share a Bt 256KB panel, m-fastest) land on one XCD's L2.
    const int lin = blockIdx.x;
    const int swz = (lin & 7) * 500 + (lin >> 3);
    const int m0 = (swz & 15) * 128;
    const int n0 = (swz >> 4) * 128;
    const int lane = tid & 63;
    const int w = tid >> 6;
    const int wr = w >> 1, wc = w & 1;
    const int fr = lane & 15, fq = lane >> 4;
    f32x4 acc[4][4] = {};
    for (int k0 = 0; k0 < HIDDEN; k0 += 32) {
        // stage A,B tiles: 512 chunks of 16B each; chunk = i*256 + tid;
        // row = chunk>>2, kq = chunk&3. LDS dest is wave-uniform; HW adds lane*16.
#pragma unroll
        for (int i = 0; i < 2; ++i) {
            const int ch = i * 256 + tid;
            const int row = ch >> 2, kq = (ch & 3) * 8;
            const __hip_bfloat16* ga = A  + (size_t)(m0 + row) * HIDDEN + k0 + kq;
            const __hip_bfloat16* gb = Bt + (size_t)(n0 + row) * HIDDEN + k0 + kq;
            __hip_bfloat16* la = At  + (size_t)((i * 256 + w * 64) * 8);
            __hip_bfloat16* lb = Bts + (size_t)((i * 256 + w * 64) * 8);
            __builtin_amdgcn_global_load_lds((const __attribute__((address_space(1))) unsigned*)ga,
                                             (__attribute__((address_space(3))) unsigned*)la, 16, 0, 0);
            __builtin_amdgcn_global_load_lds((const __attribute__((address_space(1))) unsigned*)gb,
                                             (__attribute__((address_space(3))) unsigned*)lb, 16, 0, 0);
        }
        __syncthreads();
        bf16x8 af[4], bfr[4];
#pragma unroll
        for (int mm = 0; mm < 4; ++mm)
            af[mm] = *(const bf16x8*)&At[(wr * 64 + mm * 16 + fr) * 32 + fq * 8];
#pragma unroll
        for (int nn = 0; nn < 4; ++nn)
            bfr[nn] = *(const bf16x8*)&Bts[(wc * 64 + nn * 16 + fr) * 32 + fq * 8];
#pragma unroll
        for (int mm = 0; mm < 4; ++mm)
#pragma unroll
            for (int nn = 0; nn < 4; ++nn)
                acc[mm][nn] = __builtin_amdgcn_mfma_f32_16x16x32_bf16(af[mm], bfr[nn], acc[mm][nn], 0, 0, 0);
        __syncthreads();
    }
#pragma unroll
    for (int nn = 0; nn < 4; ++nn) {
        const int col = n0 + wc * 64 + nn * 16 + fr;
        const float bias = by[col];
#pragma unroll
        for (int mm = 0; mm < 4; ++mm) {
            const int row = m0 + wr * 64 + mm * 16 + fq * 4;
            float* cp = C + (size_t)row * VOCAB + col;
            cp[0]                 = acc[mm][nn][0] + bias;
            cp[(size_t)VOCAB]     = acc[mm][nn][1] + bias;
            cp[(size_t)2 * VOCAB] = acc[mm][nn][2] + bias;
            cp[(size_t)3 * VOCAB] = acc[mm][nn][3] + bias;
        }
    }
}

extern "C" void kernel_launch(void* const* d_in, const int* in_sizes, int n_in,
                              void* d_out, int out_size, void* d_ws, size_t ws_size,
                              hipStream_t stream) {
    const int*   x   = (const int*)d_in[0];
    const float* emb = (const float*)d_in[1];
    const float* Wxh = (const float*)d_in[2];
    const float* Whh = (const float*)d_in[3];
    const float* bh  = (const float*)d_in[4];
    const float* Why = (const float*)d_in[5];
    const float* by  = (const float*)d_in[6];
    float* y = (float*)d_out;

    char* ws = (char*)d_ws;
    // layout: xh (8 MB) | hx u64[8][2][512] (64 KB) | hs bf16 (4 MB) | Wt bf16 (62.5 MB)
    const size_t off_xh = 0;
    const size_t off_hx = off_xh + (size_t)NB * NT * HIDDEN * 4;
    const size_t off_hs = off_hx + (size_t)NCH * 2 * 512 * 8;
    const size_t off_wt = off_hs + (size_t)NB * NT * HIDDEN * 2;
    const size_t need   = off_wt + (size_t)VOCAB * HIDDEN * 2;
    if (ws_size < need) return;

    float* xh = (float*)(ws + off_xh);
    unsigned long long* hx = (unsigned long long*)(ws + off_hx);
    __hip_bfloat16* hs = (__hip_bfloat16*)(ws + off_hs);
    __hip_bfloat16* Wt = (__hip_bfloat16*)(ws + off_wt);

    k_xh<<<dim3((NB * NT) / XH_ROWS), 256, 0, stream>>>(x, emb, Wxh, bh, xh);
    k_transpose<<<dim3(VOCAB / 32, HIDDEN / 32), 256, 0, stream>>>(Why, Wt);
    k_rec<<<dim3(NCH * NMEM), 256, 0, stream>>>(Whh, xh, hx, hs);
    k_proj<<<dim3((NB * NT / 128) * (VOCAB / 128)), 256, 0, stream>>>(hs, Wt, by, y);
}

// Round 8
// 981.982 us; speedup vs baseline: 1.1778x; 1.1778x over previous
//
#include <hip/hip_runtime.h>
#include <hip/hip_bf16.h>

#define VOCAB 32000
#define EMBED 512
#define HIDDEN 1024
#define NB 8
#define NT 256
#define XH_ROWS 16

#define NCH 8      // independent chains (= batch)
#define NMEM 32    // blocks per chain
#define RCOLS 32   // hidden columns per block

typedef __attribute__((ext_vector_type(8))) short bf16x8;
typedef __attribute__((ext_vector_type(4))) float f32x4;

__device__ __forceinline__ unsigned short bf16_bits(float f) {
    __hip_bfloat16 b = __float2bfloat16(f);
    unsigned short s;
    __builtin_memcpy(&s, &b, 2);
    return s;
}

// ---------------- W_hy [HIDDEN][VOCAB] f32 -> Wt [VOCAB][HIDDEN] bf16 ----------------
__global__ __launch_bounds__(256) void k_transpose(const float* __restrict__ W,
                                                   __hip_bfloat16* __restrict__ Wt) {
    __shared__ float tile[32][33];
    const int n0 = blockIdx.x * 32;
    const int k0 = blockIdx.y * 32;
    const int c = threadIdx.x & 31;
    const int r0 = threadIdx.x >> 5;
#pragma unroll
    for (int rr = 0; rr < 4; ++rr) {
        const int r = r0 + rr * 8;
        tile[c][r] = W[(size_t)(k0 + r) * VOCAB + n0 + c];
    }
    __syncthreads();
#pragma unroll
    for (int rr = 0; rr < 4; ++rr) {
        const int n = r0 + rr * 8;
        Wt[(size_t)(n0 + n) * HIDDEN + k0 + c] = __float2bfloat16(tile[n][c]);
    }
}

// ---------------- xh = emb[x] @ W_xh + b_h  (fp32) ----------------
__global__ __launch_bounds__(256) void k_xh(const int* __restrict__ ids,
                                            const float* __restrict__ emb,
                                            const float* __restrict__ Wxh,
                                            const float* __restrict__ bh,
                                            float* __restrict__ xh) {
    __shared__ alignas(16) float embS[XH_ROWS][EMBED];
    __shared__ int idsS[XH_ROWS];
    const int tid = threadIdx.x;
    const int blk = blockIdx.x;
    if (tid < XH_ROWS) idsS[tid] = ids[blk * XH_ROWS + tid];
    __syncthreads();
    const float4* emb4 = (const float4*)emb;
#pragma unroll
    for (int rep = 0; rep < (XH_ROWS * EMBED / 4) / 256; ++rep) {
        const int lin = rep * 256 + tid;
        const int r = lin >> 7;
        const int e4 = lin & 127;
        *(float4*)&embS[r][e4 * 4] = emb4[(size_t)idsS[r] * (EMBED / 4) + e4];
    }
    __syncthreads();
    float4 acc[XH_ROWS] = {};
    const float4* W4 = (const float4*)Wxh;
    for (int e = 0; e < EMBED; ++e) {
        const float4 w = W4[(size_t)e * (HIDDEN / 4) + tid];
#pragma unroll
        for (int r = 0; r < XH_ROWS; ++r) {
            const float ev = embS[r][e];
            acc[r].x += ev * w.x; acc[r].y += ev * w.y;
            acc[r].z += ev * w.z; acc[r].w += ev * w.w;
        }
    }
    const float4 bv = ((const float4*)bh)[tid];
#pragma unroll
    for (int r = 0; r < XH_ROWS; ++r) {
        float4 o;
        o.x = acc[r].x + bv.x; o.y = acc[r].y + bv.y;
        o.z = acc[r].z + bv.z; o.w = acc[r].w + bv.w;
        ((float4*)xh)[(size_t)(blk * XH_ROWS + r) * (HIDDEN / 4) + tid] = o;
    }
}

// ---------------- persistent recurrence: u64 token-in-data, 8 chains x 32 members ----------------
// One u64 = token(low16) | bf16 h[2w]<<16 | bf16 h[2w+1]<<32. Producers fire-and-forget
// relaxed agent stores; consumers poll 2 independent u64 per thread in one combined
// retry loop. Double buffer + exact-token match is deadlock-free (induction over steps)
// and replay-safe (stale tokens 255/256 never match expected 0/1).
// Bank-conflict fix (layout, not index math): hS padded to stride 68 floats/part
// -> the 4 parts of a wave read 4 distinct banks; ALL indices stay compile-time.
__global__ __launch_bounds__(256, 1) void k_rec(const float* __restrict__ Whh,
                                                const float* __restrict__ xh,
                                                unsigned long long* __restrict__ hx,
                                                __hip_bfloat16* __restrict__ hs) {
    __shared__ unsigned WstU[16 * 1032];   // [part][ii*16+col2], part-padded: 66 KB
    __shared__ float xhS[NT * RCOLS];      // 32 KB, [t][col]
    __shared__ float hS[16 * 68];          // 4.25 KB, padded: bank = ii + 4*part
    __shared__ float red[16 * 33];         // stride-33
    const int tid = threadIdx.x;
    const int bid = blockIdx.x;
    const int c = bid & (NCH - 1);     // chain (bid%8 ~ XCD round robin)
    const int m = bid >> 3;            // member 0..31
    const int j0 = m * RCOLS;
    unsigned long long* hxc = hx + (size_t)c * 1024;   // [2][512] u64 words

    // h_{-1} = 0 with token 0 lives in buf[1]; this member's 16 words
    if (tid < 16)
        __hip_atomic_store(&hxc[512 + m * 16 + tid], 0ull, __ATOMIC_RELAXED,
                           __HIP_MEMORY_SCOPE_AGENT);

    // pack W_hh slice: row i = part*64+ii, cols j0+2*col2, j0+2*col2+1
    for (int lin = tid; lin < 16 * 64 * 16; lin += 256) {
        const int part = lin >> 10;
        const int rem = lin & 1023;
        const int ii = rem >> 4;
        const int col2 = rem & 15;
        const int i = part * 64 + ii;
        const float2 w = *(const float2*)&Whh[(size_t)i * HIDDEN + j0 + 2 * col2];
        WstU[part * 1032 + ii * 16 + col2] =
            (unsigned)bf16_bits(w.x) | ((unsigned)bf16_bits(w.y) << 16);
    }
    // pre-stage this block's xh slice: [256][32]
    for (int idx = tid; idx < NT * RCOLS; idx += 256) {
        const int t = idx >> 5;
        const int col = idx & 31;
        xhS[idx] = xh[(size_t)(c * NT + t) * HIDDEN + j0 + col];
    }
    __syncthreads();

    const int col2 = tid & 15;
    const int part = tid >> 4;
    const unsigned* Wp = &WstU[part * 1032 + col2];
    const float* hp = &hS[part * 68];
    const int w0 = tid;          // u64 word indices this thread polls
    const int w1 = tid + 256;
    // padded hS staging indices: pe(e) = e + 4*(e>>6); e0 = 2*tid -> pe0 below,
    // e1 = 2*tid+512 -> pe0 + 544 (constant offset)
    const int pe0 = 2 * tid + 4 * (tid >> 5);

    for (int t = 0; t < NT; ++t) {
        unsigned long long* rbuf = hxc + ((t + 1) & 1) * 512;  // h_{t-1}, tokens == t
        unsigned long long* wbuf = hxc + (t & 1) * 512;        // we write h_t, token t+1
        const unsigned long long tok = (unsigned long long)(unsigned)t;
        // combined poll: both loads independent & in flight before the check
        unsigned long long a = __hip_atomic_load(&rbuf[w0], __ATOMIC_RELAXED, __HIP_MEMORY_SCOPE_AGENT);
        unsigned long long b = __hip_atomic_load(&rbuf[w1], __ATOMIC_RELAXED, __HIP_MEMORY_SCOPE_AGENT);
        while (((a & 0xffffull) != tok) | ((b & 0xffffull) != tok)) {
            __builtin_amdgcn_s_sleep(1);
            if ((a & 0xffffull) != tok)
                a = __hip_atomic_load(&rbuf[w0], __ATOMIC_RELAXED, __HIP_MEMORY_SCOPE_AGENT);
            if ((b & 0xffffull) != tok)
                b = __hip_atomic_load(&rbuf[w1], __ATOMIC_RELAXED, __HIP_MEMORY_SCOPE_AGENT);
        }
        *(float2*)&hS[pe0] = make_float2(__uint_as_float(((unsigned)(a >> 16) & 0xffffu) << 16),
                                         __uint_as_float(((unsigned)(a >> 32) & 0xffffu) << 16));
        *(float2*)&hS[pe0 + 544] = make_float2(__uint_as_float(((unsigned)(b >> 16) & 0xffffu) << 16),
                                               __uint_as_float(((unsigned)(b >> 32) & 0xffffu) << 16));
        __syncthreads();
        float a0 = 0.f, a1 = 0.f;
#pragma unroll 8
        for (int ii = 0; ii < 64; ++ii) {
            const unsigned u = Wp[ii * 16];
            const float hv = hp[ii];
            a0 = fmaf(__uint_as_float(u << 16), hv, a0);
            a1 = fmaf(__uint_as_float(u & 0xffff0000u), hv, a1);
        }
        red[part * 33 + 2 * col2]     = a0;
        red[part * 33 + 2 * col2 + 1] = a1;
        __syncthreads();
        if (tid < RCOLS) {
            float s = 0.f;
#pragma unroll
            for (int p = 0; p < 16; ++p) s += red[p * 33 + tid];
            const float v = tanhf(xhS[t * RCOLS + tid] + s);
            const unsigned hb = (unsigned)bf16_bits(v);
            ((unsigned short*)hs)[(size_t)(c * NT + t) * HIDDEN + j0 + tid] = (unsigned short)hb;
            const unsigned pb = (unsigned)__shfl_xor((int)hb, 1, 64);
            if ((tid & 1) == 0) {
                const unsigned long long wv = (unsigned long long)(unsigned)(t + 1)
                                            | ((unsigned long long)hb << 16)
                                            | ((unsigned long long)pb << 32);
                __hip_atomic_store(&wbuf[m * 16 + (tid >> 1)], wv, __ATOMIC_RELAXED,
                                   __HIP_MEMORY_SCOPE_AGENT);
            }
        }
        // no block barrier: next step's hS writes are gated by the token poll,
        // which can't pass until this block produced its own words.
    }
}

// ---------------- y = hs @ Wt^T + b_y  (bf16 MFMA, m97-style: global_load_lds) ----------------
__global__ __launch_bounds__(256) void k_proj(const __hip_bfloat16* __restrict__ A,   // [2048][1024]
                                              const __hip_bfloat16* __restrict__ Bt,  // [32000][1024]
                                              const float* __restrict__ by,
                                              float* __restrict__ C) {
    __shared__ __hip_bfloat16 At[128 * 32];    // linear: required by global_load_lds
    __shared__ __hip_bfloat16 Bts[128 * 32];
    const int tid = threadIdx.x;
    // bijective XCD-chunked swizzle (4000 % 8 == 0): consecutive swz ids (which
    // share a Bt 256KB panel, m-fastest) land on one XCD's L2.
    const int lin = blockIdx.x;
    const int swz = (lin & 7) * 500 + (lin >> 3);
    const int m0 = (swz & 15) * 128;
    const int n0 = (swz >> 4) * 128;
    const int lane = tid & 63;
    const int w = tid >> 6;
    const int wr = w >> 1, wc = w & 1;
    const int fr = lane & 15, fq = lane >> 4;
    f32x4 acc[4][4] = {};
    for (int k0 = 0; k0 < HIDDEN; k0 += 32) {
        // stage A,B tiles: 512 chunks of 16B each; chunk = i*256 + tid;
        // row = chunk>>2, kq = chunk&3. LDS dest is wave-uniform; HW adds lane*16.
#pragma unroll
        for (int i = 0; i < 2; ++i) {
            const int ch = i * 256 + tid;
            const int row = ch >> 2, kq = (ch & 3) * 8;
            const __hip_bfloat16* ga = A  + (size_t)(m0 + row) * HIDDEN + k0 + kq;
            const __hip_bfloat16* gb = Bt + (size_t)(n0 + row) * HIDDEN + k0 + kq;
            __hip_bfloat16* la = At  + (size_t)((i * 256 + w * 64) * 8);
            __hip_bfloat16* lb = Bts + (size_t)((i * 256 + w * 64) * 8);
            __builtin_amdgcn_global_load_lds((const __attribute__((address_space(1))) unsigned*)ga,
                                             (__attribute__((address_space(3))) unsigned*)la, 16, 0, 0);
            __builtin_amdgcn_global_load_lds((const __attribute__((address_space(1))) unsigned*)gb,
                                             (__attribute__((address_space(3))) unsigned*)lb, 16, 0, 0);
        }
        __syncthreads();
        bf16x8 af[4], bfr[4];
#pragma unroll
        for (int mm = 0; mm < 4; ++mm)
            af[mm] = *(const bf16x8*)&At[(wr * 64 + mm * 16 + fr) * 32 + fq * 8];
#pragma unroll
        for (int nn = 0; nn < 4; ++nn)
            bfr[nn] = *(const bf16x8*)&Bts[(wc * 64 + nn * 16 + fr) * 32 + fq * 8];
#pragma unroll
        for (int mm = 0; mm < 4; ++mm)
#pragma unroll
            for (int nn = 0; nn < 4; ++nn)
                acc[mm][nn] = __builtin_amdgcn_mfma_f32_16x16x32_bf16(af[mm], bfr[nn], acc[mm][nn], 0, 0, 0);
        __syncthreads();
    }
#pragma unroll
    for (int nn = 0; nn < 4; ++nn) {
        const int col = n0 + wc * 64 + nn * 16 + fr;
        const float bias = by[col];
#pragma unroll
        for (int mm = 0; mm < 4; ++mm) {
            const int row = m0 + wr * 64 + mm * 16 + fq * 4;
            float* cp = C + (size_t)row * VOCAB + col;
            cp[0]                 = acc[mm][nn][0] + bias;
            cp[(size_t)VOCAB]     = acc[mm][nn][1] + bias;
            cp[(size_t)2 * VOCAB] = acc[mm][nn][2] + bias;
            cp[(size_t)3 * VOCAB] = acc[mm][nn][3] + bias;
        }
    }
}

extern "C" void kernel_launch(void* const* d_in, const int* in_sizes, int n_in,
                              void* d_out, int out_size, void* d_ws, size_t ws_size,
                              hipStream_t stream) {
    const int*   x   = (const int*)d_in[0];
    const float* emb = (const float*)d_in[1];
    const float* Wxh = (const float*)d_in[2];
    const float* Whh = (const float*)d_in[3];
    const float* bh  = (const float*)d_in[4];
    const float* Why = (const float*)d_in[5];
    const float* by  = (const float*)d_in[6];
    float* y = (float*)d_out;

    char* ws = (char*)d_ws;
    // layout: xh (8 MB) | hx u64[8][2][512] (64 KB) | hs bf16 (4 MB) | Wt bf16 (62.5 MB)
    const size_t off_xh = 0;
    const size_t off_hx = off_xh + (size_t)NB * NT * HIDDEN * 4;
    const size_t off_hs = off_hx + (size_t)NCH * 2 * 512 * 8;
    const size_t off_wt = off_hs + (size_t)NB * NT * HIDDEN * 2;
    const size_t need   = off_wt + (size_t)VOCAB * HIDDEN * 2;
    if (ws_size < need) return;

    float* xh = (float*)(ws + off_xh);
    unsigned long long* hx = (unsigned long long*)(ws + off_hx);
    __hip_bfloat16* hs = (__hip_bfloat16*)(ws + off_hs);
    __hip_bfloat16* Wt = (__hip_bfloat16*)(ws + off_wt);

    k_xh<<<dim3((NB * NT) / XH_ROWS), 256, 0, stream>>>(x, emb, Wxh, bh, xh);
    k_transpose<<<dim3(VOCAB / 32, HIDDEN / 32), 256, 0, stream>>>(Why, Wt);
    k_rec<<<dim3(NCH * NMEM), 256, 0, stream>>>(Whh, xh, hx, hs);
    k_proj<<<dim3((NB * NT / 128) * (VOCAB / 128)), 256, 0, stream>>>(hs, Wt, by, y);
}